// Round 1
// baseline (415.693 us; speedup 1.0000x reference)
//
#include <hip/hip_runtime.h>

typedef __attribute__((ext_vector_type(8))) short short8;
typedef __attribute__((ext_vector_type(4))) float f32x4;
typedef __attribute__((ext_vector_type(4))) unsigned short u16x4;

#define LOG2E 1.4426950408889634f

static __device__ __forceinline__ unsigned short f2bf(float f) {
  unsigned int u = __float_as_uint(f);
  u += 0x7fffu + ((u >> 16) & 1u);
  return (unsigned short)(u >> 16);
}

// ---- cast kernels ----------------------------------------------------------
__global__ void k_cast_x(const float* __restrict__ x, unsigned short* __restrict__ xb) {
  int i = blockIdx.x * blockDim.x + threadIdx.x;   // 1572864 threads, 4 elems each
  float4 v = reinterpret_cast<const float4*>(x)[i];
  u16x4 o;
  o.x = f2bf(v.x); o.y = f2bf(v.y); o.z = f2bf(v.z); o.w = f2bf(v.w);
  reinterpret_cast<u16x4*>(xb)[i] = o;
}

// qkv_w [384][576] -> wt [576][384] bf16 (B^T layout for MFMA B-fragments)
__global__ void k_cast_wqkv(const float* __restrict__ w, unsigned short* __restrict__ wt) {
  int i = blockIdx.x * blockDim.x + threadIdx.x;   // 221184
  int c = i / 384, k = i % 384;
  wt[i] = f2bf(w[k * 576 + c]);
}

// proj_w [192][384] -> wt [384][192] bf16
__global__ void k_cast_wproj(const float* __restrict__ w, unsigned short* __restrict__ wt) {
  int i = blockIdx.x * blockDim.x + threadIdx.x;   // 73728
  int c = i / 192, k = i % 192;
  wt[i] = f2bf(w[k * 384 + c]);
}

// ---- QKV GEMM: [16384,384] @ [384,576] + b -> Q(,K)[b,h,n,32], V^T[b,h,32,n]
__global__ __launch_bounds__(256) void k_qkv(const unsigned short* __restrict__ xb,
                                             const unsigned short* __restrict__ wt,
                                             const float* __restrict__ bias,
                                             unsigned short* __restrict__ Qb,
                                             unsigned short* __restrict__ Kb,
                                             unsigned short* __restrict__ Vt) {
  int w = threadIdx.x >> 6, lane = threadIdx.x & 63, lo = lane & 15, hi = lane >> 4;
  int wg = blockIdx.x * 4 + w;        // 9216 waves: 1024 row-tiles x 9 col-groups
  int rt = wg / 9, cg = wg % 9;
  int r0 = rt * 16, c0 = cg * 64;
  const f32x4 z = {0.f, 0.f, 0.f, 0.f};
  f32x4 acc[4] = {z, z, z, z};
  for (int t = 0; t < 12; ++t) {
    short8 a = *reinterpret_cast<const short8*>(xb + (r0 + lo) * 384 + t * 32 + hi * 8);
#pragma unroll
    for (int j = 0; j < 4; ++j) {
      short8 b = *reinterpret_cast<const short8*>(wt + (c0 + j * 16 + lo) * 384 + t * 32 + hi * 8);
      acc[j] = __builtin_amdgcn_mfma_f32_16x16x32_bf16(a, b, acc[j], 0, 0, 0);
    }
  }
#pragma unroll
  for (int j = 0; j < 4; ++j) {
    int colbase = c0 + j * 16;          // multiple of 16; never straddles q/k/v or head
    int which = colbase / 192;
    int rem = colbase % 192;
    int h = rem / 32;
    int d = (rem % 32) + lo;
    float bv = bias[colbase + lo];
#pragma unroll
    for (int r = 0; r < 4; ++r) {
      int row = r0 + hi * 4 + r;
      int b_ = row >> 12, n = row & 4095;
      int bh = b_ * 6 + h;
      float v = acc[j][r] + bv;
      if (which == 0)      Qb[(bh * 4096 + n) * 32 + d] = f2bf(v * 0.125f);  // pre-scale, exact
      else if (which == 1) Kb[(bh * 4096 + n) * 32 + d] = f2bf(v);
      else                 Vt[(bh * 32 + d) * 4096 + n] = f2bf(v);
    }
  }
}

// ---- flash attention: per block one (b,h) x 64 q-rows; 4 waves x 16 rows ----
__global__ __launch_bounds__(256) void k_attn(const unsigned short* __restrict__ Qb,
                                              const unsigned short* __restrict__ Kb,
                                              const unsigned short* __restrict__ Vt,
                                              unsigned short* __restrict__ AO) {
  __shared__ __align__(16) unsigned short P[4][1024];  // per-wave 16x64 bf16, XOR-swizzled
  int w = threadIdx.x >> 6, lane = threadIdx.x & 63, lo = lane & 15, hi = lane >> 4;
  int bh = blockIdx.x >> 6, qt = blockIdx.x & 63;
  int b_ = bh / 6, h = bh % 6;
  int qbase = qt * 64 + w * 16;
  const unsigned short* Kp = Kb + bh * 4096 * 32;
  const unsigned short* Vp = Vt + bh * 32 * 4096;
  short8 qf = *reinterpret_cast<const short8*>(Qb + (bh * 4096 + qbase + lo) * 32 + hi * 8);
  const f32x4 z = {0.f, 0.f, 0.f, 0.f};
  f32x4 oacc[2] = {z, z};
  float m[4] = {-1e30f, -1e30f, -1e30f, -1e30f};
  float l[4] = {0.f, 0.f, 0.f, 0.f};
  int sw = (lo & 7) << 3;

  for (int kv0 = 0; kv0 < 4096; kv0 += 64) {
    f32x4 s[4];
#pragma unroll
    for (int kk = 0; kk < 4; ++kk) {
      short8 kf = *reinterpret_cast<const short8*>(Kp + (kv0 + kk * 16 + lo) * 32 + hi * 8);
      s[kk] = __builtin_amdgcn_mfma_f32_16x16x32_bf16(qf, kf, z, 0, 0, 0);
    }
    // row stats: row = hi*4+r, cols spread over the 16 lanes sharing hi
    float tmax[4], tsum[4], mnew[4], fac[4];
#pragma unroll
    for (int r = 0; r < 4; ++r)
      tmax[r] = fmaxf(fmaxf(s[0][r], s[1][r]), fmaxf(s[2][r], s[3][r]));
#pragma unroll
    for (int msk = 1; msk < 16; msk <<= 1)
#pragma unroll
      for (int r = 0; r < 4; ++r)
        tmax[r] = fmaxf(tmax[r], __shfl_xor(tmax[r], msk));
#pragma unroll
    for (int r = 0; r < 4; ++r) {
      mnew[r] = fmaxf(m[r], tmax[r]);
      fac[r] = exp2f((m[r] - mnew[r]) * LOG2E);
      tsum[r] = 0.f;
    }
#pragma unroll
    for (int kk = 0; kk < 4; ++kk)
#pragma unroll
      for (int r = 0; r < 4; ++r) {
        float p = exp2f((s[kk][r] - mnew[r]) * LOG2E);
        tsum[r] += p;
        int row = hi * 4 + r;
        P[w][row * 64 + ((kk * 16 + lo) ^ ((row & 7) << 3))] = f2bf(p);
      }
#pragma unroll
    for (int msk = 1; msk < 16; msk <<= 1)
#pragma unroll
      for (int r = 0; r < 4; ++r)
        tsum[r] += __shfl_xor(tsum[r], msk);
#pragma unroll
    for (int r = 0; r < 4; ++r) {
      l[r] = l[r] * fac[r] + tsum[r];
      m[r] = mnew[r];
      oacc[0][r] *= fac[r];
      oacc[1][r] *= fac[r];
    }
    __syncthreads();   // P buffer is wave-private; barrier kept for round-0 safety
#pragma unroll
    for (int kk2 = 0; kk2 < 2; ++kk2) {
      short8 pa = *reinterpret_cast<const short8*>(&P[w][lo * 64 + ((kk2 * 32 + hi * 8) ^ sw)]);
#pragma unroll
      for (int dh = 0; dh < 2; ++dh) {
        short8 vf = *reinterpret_cast<const short8*>(Vp + (dh * 16 + lo) * 4096 + kv0 + kk2 * 32 + hi * 8);
        oacc[dh] = __builtin_amdgcn_mfma_f32_16x16x32_bf16(pa, vf, oacc[dh], 0, 0, 0);
      }
    }
  }
  // epilogue: AO layout [b][n][h*32+d] so proj GEMM reads contiguous 192-rows
#pragma unroll
  for (int r = 0; r < 4; ++r) {
    float inv = 1.0f / l[r];
    int qrow = qbase + hi * 4 + r;
#pragma unroll
    for (int dh = 0; dh < 2; ++dh)
      AO[(b_ * 4096 + qrow) * 192 + h * 32 + dh * 16 + lo] = f2bf(oacc[dh][r] * inv);
  }
}

// ---- proj GEMM: [16384,192] @ [192,384] + b -> out fp32 --------------------
__global__ __launch_bounds__(256) void k_proj(const unsigned short* __restrict__ AO,
                                              const unsigned short* __restrict__ wt,
                                              const float* __restrict__ bias,
                                              float* __restrict__ out) {
  int w = threadIdx.x >> 6, lane = threadIdx.x & 63, lo = lane & 15, hi = lane >> 4;
  int wg = blockIdx.x * 4 + w;        // 6144 waves: 1024 row-tiles x 6 col-groups
  int rt = wg / 6, cg = wg % 6;
  int r0 = rt * 16, c0 = cg * 64;
  const f32x4 z = {0.f, 0.f, 0.f, 0.f};
  f32x4 acc[4] = {z, z, z, z};
  for (int t = 0; t < 6; ++t) {
    short8 a = *reinterpret_cast<const short8*>(AO + (r0 + lo) * 192 + t * 32 + hi * 8);
#pragma unroll
    for (int j = 0; j < 4; ++j) {
      short8 b = *reinterpret_cast<const short8*>(wt + (c0 + j * 16 + lo) * 192 + t * 32 + hi * 8);
      acc[j] = __builtin_amdgcn_mfma_f32_16x16x32_bf16(a, b, acc[j], 0, 0, 0);
    }
  }
#pragma unroll
  for (int j = 0; j < 4; ++j) {
    int col = c0 + j * 16 + lo;
    float bv = bias[col];
#pragma unroll
    for (int r = 0; r < 4; ++r) {
      int row = r0 + hi * 4 + r;
      out[row * 384 + col] = acc[j][r] + bv;
    }
  }
}

// ---- launch ----------------------------------------------------------------
extern "C" void kernel_launch(void* const* d_in, const int* in_sizes, int n_in,
                              void* d_out, int out_size, void* d_ws, size_t ws_size,
                              hipStream_t stream) {
  const float* x      = (const float*)d_in[0];
  const float* qkv_w  = (const float*)d_in[1];
  const float* qkv_b  = (const float*)d_in[2];
  const float* proj_w = (const float*)d_in[3];
  const float* proj_b = (const float*)d_in[4];
  float* out = (float*)d_out;
  char* ws = (char*)d_ws;

  unsigned short* xb    = (unsigned short*)(ws);                 // 12,582,912 B
  unsigned short* wqkvt = (unsigned short*)(ws + 12582912);      //    442,368 B
  unsigned short* wpt   = (unsigned short*)(ws + 13025280);      //    147,456 B
  unsigned short* Qb    = (unsigned short*)(ws + 13172736);      //  6,291,456 B
  unsigned short* Kb    = (unsigned short*)(ws + 19464192);      //  6,291,456 B
  unsigned short* Vt    = (unsigned short*)(ws + 25755648);      //  6,291,456 B
  unsigned short* AO    = (unsigned short*)(ws + 32047104);      //  6,291,456 B

  k_cast_x   <<<6144, 256, 0, stream>>>(x, xb);
  k_cast_wqkv<<< 864, 256, 0, stream>>>(qkv_w, wqkvt);
  k_cast_wproj<<<288, 256, 0, stream>>>(proj_w, wpt);
  k_qkv      <<<2304, 256, 0, stream>>>(xb, wqkvt, qkv_b, Qb, Kb, Vt);
  k_attn     <<<1536, 256, 0, stream>>>(Qb, Kb, Vt, AO);
  k_proj     <<<1536, 256, 0, stream>>>(AO, wpt, proj_b, out);
}

// Round 2
// 237.925 us; speedup vs baseline: 1.7472x; 1.7472x over previous
//
#include <hip/hip_runtime.h>

typedef __attribute__((ext_vector_type(8))) short short8;
typedef __attribute__((ext_vector_type(4))) float f32x4;
typedef __attribute__((ext_vector_type(16))) float f32x16;
typedef __attribute__((ext_vector_type(4))) unsigned short u16x4;
typedef __attribute__((ext_vector_type(2))) unsigned int u32x2;
typedef __attribute__((ext_vector_type(4))) unsigned int u32x4;

#define LOG2E 1.4426950408889634f

#if __has_builtin(__builtin_amdgcn_exp2f)
#define EXP2(x) __builtin_amdgcn_exp2f(x)
#else
#define EXP2(x) exp2f(x)
#endif

static __device__ __forceinline__ unsigned short f2bf(float f) {
  unsigned int u = __float_as_uint(f);
  u += 0x7fffu + ((u >> 16) & 1u);
  return (unsigned short)(u >> 16);
}

// exchange: a' = {a.lo32, b.lo32(partner)}, b' = {a.hi32(partner), b.hi32}
static __device__ __forceinline__ void swap32(unsigned& a, unsigned& b) {
#if __has_builtin(__builtin_amdgcn_permlane32_swap)
  u32x2 r = __builtin_amdgcn_permlane32_swap(a, b, false, false);
  a = r.x; b = r.y;
#else
  unsigned pa = (unsigned)__shfl_xor((int)a, 32);
  unsigned pb = (unsigned)__shfl_xor((int)b, 32);
  bool hi = (threadIdx.x & 32) != 0;
  unsigned na = hi ? pb : a;
  unsigned nb = hi ? b : pa;
  a = na; b = nb;
#endif
}

// ---- cast kernels ----------------------------------------------------------
__global__ void k_cast_x(const float* __restrict__ x, unsigned short* __restrict__ xb) {
  int i = blockIdx.x * blockDim.x + threadIdx.x;
  float4 v = reinterpret_cast<const float4*>(x)[i];
  u16x4 o;
  o.x = f2bf(v.x); o.y = f2bf(v.y); o.z = f2bf(v.z); o.w = f2bf(v.w);
  reinterpret_cast<u16x4*>(xb)[i] = o;
}

__global__ void k_cast_wqkv(const float* __restrict__ w, unsigned short* __restrict__ wt) {
  int i = blockIdx.x * blockDim.x + threadIdx.x;   // 221184
  int c = i / 384, k = i % 384;
  wt[i] = f2bf(w[k * 576 + c]);
}

__global__ void k_cast_wproj(const float* __restrict__ w, unsigned short* __restrict__ wt) {
  int i = blockIdx.x * blockDim.x + threadIdx.x;   // 73728
  int c = i / 192, k = i % 192;
  wt[i] = f2bf(w[k * 384 + c]);
}

// ---- QKV GEMM --------------------------------------------------------------
__global__ __launch_bounds__(256) void k_qkv(const unsigned short* __restrict__ xb,
                                             const unsigned short* __restrict__ wt,
                                             const float* __restrict__ bias,
                                             unsigned short* __restrict__ Qb,
                                             unsigned short* __restrict__ Kb,
                                             unsigned short* __restrict__ Vt) {
  int w = threadIdx.x >> 6, lane = threadIdx.x & 63, lo = lane & 15, hi = lane >> 4;
  int wg = blockIdx.x * 4 + w;
  int rt = wg / 9, cg = wg % 9;
  int r0 = rt * 16, c0 = cg * 64;
  const f32x4 z = {0.f, 0.f, 0.f, 0.f};
  f32x4 acc[4] = {z, z, z, z};
  for (int t = 0; t < 12; ++t) {
    short8 a = *reinterpret_cast<const short8*>(xb + (r0 + lo) * 384 + t * 32 + hi * 8);
#pragma unroll
    for (int j = 0; j < 4; ++j) {
      short8 b = *reinterpret_cast<const short8*>(wt + (c0 + j * 16 + lo) * 384 + t * 32 + hi * 8);
      acc[j] = __builtin_amdgcn_mfma_f32_16x16x32_bf16(a, b, acc[j], 0, 0, 0);
    }
  }
#pragma unroll
  for (int j = 0; j < 4; ++j) {
    int colbase = c0 + j * 16;
    int which = colbase / 192;
    int rem = colbase % 192;
    int h = rem / 32;
    int d = (rem % 32) + lo;
    float bv = bias[colbase + lo];
#pragma unroll
    for (int r = 0; r < 4; ++r) {
      int row = r0 + hi * 4 + r;
      int b_ = row >> 12, n = row & 4095;
      int bh = b_ * 6 + h;
      float v = acc[j][r] + bv;
      if (which == 0)      Qb[(bh * 4096 + n) * 32 + d] = f2bf(v * 0.125f);
      else if (which == 1) Kb[(bh * 4096 + n) * 32 + d] = f2bf(v);
      else                 Vt[(bh * 32 + d) * 4096 + n] = f2bf(v);
    }
  }
}

// ---- flash attention: swapped QK^T, in-register softmax, no LDS ------------
// Block = 4 waves, each wave independent: 32 q-rows, KVBLK=32.
// S^T tile = mfma_32x32x16(K,Q): lane(q=lane&31,h1=lane>>5) holds
// S[q][k=(r&3)+8*(r>>2)+4*h1], r=0..15.
__global__ __launch_bounds__(256) void k_attn(const unsigned short* __restrict__ Qb,
                                              const unsigned short* __restrict__ Kb,
                                              const unsigned short* __restrict__ Vt,
                                              unsigned short* __restrict__ AO) {
  int lane = threadIdx.x & 63, w = threadIdx.x >> 6;
  int l31 = lane & 31, h1 = lane >> 5;
  int lb = (blockIdx.x & 7) * 96 + (blockIdx.x >> 3);   // XCD swizzle (768 % 8 == 0)
  int bh = lb >> 5, qt = lb & 31;
  int b_ = bh / 6, h = bh % 6;
  int qb = qt * 128 + w * 32;

  const unsigned short* Qp = Qb + (bh * 4096 + qb) * 32;
  const unsigned short* Kp = Kb + bh * 4096 * 32;
  const unsigned short* Vp = Vt + bh * 32 * 4096;

  short8 q0 = *reinterpret_cast<const short8*>(Qp + l31 * 32 + h1 * 8);
  short8 q1 = *reinterpret_cast<const short8*>(Qp + l31 * 32 + 16 + h1 * 8);

  const unsigned short* ka = Kp + l31 * 32 + h1 * 8;
  const unsigned short* va = Vp + l31 * 4096 + h1 * 8;
  short8 ck0 = *reinterpret_cast<const short8*>(ka);
  short8 ck1 = *reinterpret_cast<const short8*>(ka + 16);
  short8 cv0 = *reinterpret_cast<const short8*>(va);
  short8 cv1 = *reinterpret_cast<const short8*>(va + 16);

  f32x16 o = {};
  float m = -1e30f, l = 0.f, mm = 0.f;

  for (int t = 0; t < 128; ++t) {
    short8 nk0, nk1, nv0, nv1;
    if (t < 127) {
      ka += 32 * 32; va += 32;
      nk0 = *reinterpret_cast<const short8*>(ka);
      nk1 = *reinterpret_cast<const short8*>(ka + 16);
      nv0 = *reinterpret_cast<const short8*>(va);
      nv1 = *reinterpret_cast<const short8*>(va + 16);
    }
    f32x16 z = {};
    f32x16 s = __builtin_amdgcn_mfma_f32_32x32x16_bf16(ck0, q0, z, 0, 0, 0);
    s = __builtin_amdgcn_mfma_f32_32x32x16_bf16(ck1, q1, s, 0, 0, 0);

    // row max: in-lane tree over 16 + cross-half
    float x8[8], x4[4];
#pragma unroll
    for (int i = 0; i < 8; ++i) x8[i] = fmaxf(s[i], s[i + 8]);
#pragma unroll
    for (int i = 0; i < 4; ++i) x4[i] = fmaxf(x8[i], x8[i + 4]);
    float pm = fmaxf(fmaxf(x4[0], x4[1]), fmaxf(x4[2], x4[3]));
    pm = fmaxf(pm, __shfl_xor(pm, 32));

    if (!__all(pm - m <= 8.0f)) {               // defer-max (T13)
      float mn = fmaxf(m, pm);
      float fac = EXP2((m - mn) * LOG2E);
      l *= fac;
#pragma unroll
      for (int r = 0; r < 16; ++r) o[r] *= fac;
      m = mn;
      mm = -m * LOG2E;
    }

    float p[16];
#pragma unroll
    for (int r = 0; r < 16; ++r) p[r] = EXP2(fmaf(s[r], LOG2E, mm));

    // row-sum partial (own 16 k's only; cross-half combine deferred to end)
    float s8[8], s4[4];
#pragma unroll
    for (int i = 0; i < 8; ++i) s8[i] = p[i] + p[i + 8];
#pragma unroll
    for (int i = 0; i < 4; ++i) s4[i] = s8[i] + s8[i + 4];
    l += (s4[0] + s4[1]) + (s4[2] + s4[3]);

    // pack P -> PV B-fragments: chunk0 (k 0..15) from p[0..7], chunk1 from p[8..15]
    unsigned w0, w1, w2, w3, w4, w5, w6, w7;
    asm("v_cvt_pk_bf16_f32 %0, %1, %2" : "=v"(w0) : "v"(p[0]), "v"(p[1]));
    asm("v_cvt_pk_bf16_f32 %0, %1, %2" : "=v"(w1) : "v"(p[2]), "v"(p[3]));
    asm("v_cvt_pk_bf16_f32 %0, %1, %2" : "=v"(w2) : "v"(p[4]), "v"(p[5]));
    asm("v_cvt_pk_bf16_f32 %0, %1, %2" : "=v"(w3) : "v"(p[6]), "v"(p[7]));
    asm("v_cvt_pk_bf16_f32 %0, %1, %2" : "=v"(w4) : "v"(p[8]), "v"(p[9]));
    asm("v_cvt_pk_bf16_f32 %0, %1, %2" : "=v"(w5) : "v"(p[10]), "v"(p[11]));
    asm("v_cvt_pk_bf16_f32 %0, %1, %2" : "=v"(w6) : "v"(p[12]), "v"(p[13]));
    asm("v_cvt_pk_bf16_f32 %0, %1, %2" : "=v"(w7) : "v"(p[14]), "v"(p[15]));
    swap32(w0, w2);   // -> words 0,2 of chunk0
    swap32(w1, w3);   // -> words 1,3 of chunk0
    swap32(w4, w6);
    swap32(w5, w7);
    u32x4 pb0v = {w0, w1, w2, w3};
    u32x4 pb1v = {w4, w5, w6, w7};
    short8 pb0 = __builtin_bit_cast(short8, pb0v);
    short8 pb1 = __builtin_bit_cast(short8, pb1v);

    o = __builtin_amdgcn_mfma_f32_32x32x16_bf16(cv0, pb0, o, 0, 0, 0);
    o = __builtin_amdgcn_mfma_f32_32x32x16_bf16(cv1, pb1, o, 0, 0, 0);

    ck0 = nk0; ck1 = nk1; cv0 = nv0; cv1 = nv1;
  }

  float lt = l + __shfl_xor(l, 32);
  float inv = 1.0f / lt;
  unsigned short* aop = AO + (b_ * 4096 + qb + l31) * 192 + h * 32 + h1 * 4;
#pragma unroll
  for (int qd = 0; qd < 4; ++qd) {
    u16x4 st;
    st.x = f2bf(o[qd * 4 + 0] * inv);
    st.y = f2bf(o[qd * 4 + 1] * inv);
    st.z = f2bf(o[qd * 4 + 2] * inv);
    st.w = f2bf(o[qd * 4 + 3] * inv);
    *reinterpret_cast<u16x4*>(aop + qd * 8) = st;
  }
}

// ---- proj GEMM -------------------------------------------------------------
__global__ __launch_bounds__(256) void k_proj(const unsigned short* __restrict__ AO,
                                              const unsigned short* __restrict__ wt,
                                              const float* __restrict__ bias,
                                              float* __restrict__ out) {
  int w = threadIdx.x >> 6, lane = threadIdx.x & 63, lo = lane & 15, hi = lane >> 4;
  int wg = blockIdx.x * 4 + w;
  int rt = wg / 6, cg = wg % 6;
  int r0 = rt * 16, c0 = cg * 64;
  const f32x4 z = {0.f, 0.f, 0.f, 0.f};
  f32x4 acc[4] = {z, z, z, z};
  for (int t = 0; t < 6; ++t) {
    short8 a = *reinterpret_cast<const short8*>(AO + (r0 + lo) * 192 + t * 32 + hi * 8);
#pragma unroll
    for (int j = 0; j < 4; ++j) {
      short8 b = *reinterpret_cast<const short8*>(wt + (c0 + j * 16 + lo) * 192 + t * 32 + hi * 8);
      acc[j] = __builtin_amdgcn_mfma_f32_16x16x32_bf16(a, b, acc[j], 0, 0, 0);
    }
  }
#pragma unroll
  for (int j = 0; j < 4; ++j) {
    int col = c0 + j * 16 + lo;
    float bv = bias[col];
#pragma unroll
    for (int r = 0; r < 4; ++r) {
      int row = r0 + hi * 4 + r;
      out[row * 384 + col] = acc[j][r] + bv;
    }
  }
}

// ---- launch ----------------------------------------------------------------
extern "C" void kernel_launch(void* const* d_in, const int* in_sizes, int n_in,
                              void* d_out, int out_size, void* d_ws, size_t ws_size,
                              hipStream_t stream) {
  const float* x      = (const float*)d_in[0];
  const float* qkv_w  = (const float*)d_in[1];
  const float* qkv_b  = (const float*)d_in[2];
  const float* proj_w = (const float*)d_in[3];
  const float* proj_b = (const float*)d_in[4];
  float* out = (float*)d_out;
  char* ws = (char*)d_ws;

  unsigned short* xb    = (unsigned short*)(ws);
  unsigned short* wqkvt = (unsigned short*)(ws + 12582912);
  unsigned short* wpt   = (unsigned short*)(ws + 13025280);
  unsigned short* Qb    = (unsigned short*)(ws + 13172736);
  unsigned short* Kb    = (unsigned short*)(ws + 19464192);
  unsigned short* Vt    = (unsigned short*)(ws + 25755648);
  unsigned short* AO    = (unsigned short*)(ws + 32047104);

  k_cast_x   <<<6144, 256, 0, stream>>>(x, xb);
  k_cast_wqkv<<< 864, 256, 0, stream>>>(qkv_w, wqkvt);
  k_cast_wproj<<<288, 256, 0, stream>>>(proj_w, wpt);
  k_qkv      <<<2304, 256, 0, stream>>>(xb, wqkvt, qkv_b, Qb, Kb, Vt);
  k_attn     <<< 768, 256, 0, stream>>>(Qb, Kb, Vt, AO);
  k_proj     <<<1536, 256, 0, stream>>>(AO, wpt, proj_b, out);
}